// Round 15
// baseline (496.420 us; speedup 1.0000x reference)
//
#include <hip/hip_runtime.h>
#include <hip/hip_bf16.h>
#include <math.h>

#define NN   20000
#define NE   640000
#define HD   128
#define EDIM 16
#define KIN  273
#define P2   136      // LDS pitch (ushorts), row stride 272 B (16B-aligned)

#define S_PWT   4096    // We1 tail:   1 kb x 8 nb x 512 (i8-packed cols)
#define S_PWE1M 32768   // We1 main:   8 kb x 8 nb x 512 (interleave-2, pre only)
#define S_PW4   16384   // We2/Wx1:    4 kb x 8 nb x 512 (i8-packed cols)
#define S_PWH1  32768   // Wh1:        8 kb x 8 nb x 512 (identity cols)
#define S_PWH2  16384   // Wh2:        4 kb x 8 nb x 512 (identity cols)

typedef __bf16 bf16x8 __attribute__((ext_vector_type(8)));
typedef float  f32x4  __attribute__((ext_vector_type(4)));

__device__ __forceinline__ float silu_f(float v) {
    const float e = __expf(-v);
    return v * __builtin_amdgcn_rcpf(1.0f + e);
}
__device__ __forceinline__ float tanh_f(float s) {
    const float e = __expf(2.0f * s);
    return 1.0f - 2.0f * __builtin_amdgcn_rcpf(e + 1.0f);
}
__device__ __forceinline__ unsigned short f2bf(float f) {
    __bf16 b = (__bf16)f;
    return __builtin_bit_cast(unsigned short, b);
}
__device__ __forceinline__ float bf2f(unsigned short u) {
    __bf16 b = __builtin_bit_cast(__bf16, u);
    return (float)b;
}
__device__ __forceinline__ unsigned pack2bf(float a, float b) {
    return (unsigned)f2bf(a) | ((unsigned)f2bf(b) << 16);
}
__device__ __forceinline__ float lo16(unsigned u) { return bf2f((unsigned short)(u & 0xffff)); }
__device__ __forceinline__ float hi16(unsigned u) { return bf2f((unsigned short)(u >> 16)); }

// identity pack (node): elem[lane*8+j] = W[kb*32+(lane>>4)*8+j][nb*16+(lane&15)]
__device__ __forceinline__ void pack_id(const float* __restrict__ W, int Kreal,
                                        unsigned short* __restrict__ P, int idx) {
    const int f = idx >> 9, r = idx & 511;
    const int lane = r >> 3, j = r & 7;
    const int kb = f >> 3, nb = f & 7;
    const int k = kb * 32 + (lane >> 4) * 8 + j;
    const int n = nb * 16 + (lane & 15);
    P[idx] = f2bf((k < Kreal) ? W[(size_t)k * HD + n] : 0.0f);
}
// interleave-2 pack (pre kernel only): n = (nb>>1)*32 + 2*(lane&15) + (nb&1)
__device__ __forceinline__ void pack_il(const float* __restrict__ W, int Kreal,
                                        unsigned short* __restrict__ P, int idx) {
    const int f = idx >> 9, r = idx & 511;
    const int lane = r >> 3, j = r & 7;
    const int kb = f >> 3, nb = f & 7;
    const int k = kb * 32 + (lane >> 4) * 8 + j;
    const int n = (nb >> 1) * 32 + 2 * (lane & 15) + (nb & 1);
    P[idx] = f2bf((k < Kreal) ? W[(size_t)k * HD + n] : 0.0f);
}
// i8 pack (edge: thread l16 owns 8 adjacent cols): n = 8*(lane&15) + nb
__device__ __forceinline__ void pack_i8(const float* __restrict__ W, int Kreal,
                                        unsigned short* __restrict__ P, int idx) {
    const int f = idx >> 9, r = idx & 511;
    const int lane = r >> 3, j = r & 7;
    const int kb = f >> 3, nb = f & 7;
    const int k = kb * 32 + (lane >> 4) * 8 + j;
    const int n = 8 * (lane & 15) + nb;
    P[idx] = f2bf((k < Kreal) ? W[(size_t)k * HD + n] : 0.0f);
}

// ===== prep: zero msg/coord + cast h + pack all weights + dst histogram =====
#define ZDW (NN*(HD+3))

__global__ void egnn_prep_kernel(
    const float* __restrict__ h, const int* __restrict__ ei,
    const float* __restrict__ We1, const float* __restrict__ We2,
    const float* __restrict__ Wx1, const float* __restrict__ Wh1,
    const float* __restrict__ Wh2,
    int* __restrict__ zbase,
    unsigned short* __restrict__ hb,
    unsigned short* __restrict__ PWt,  unsigned short* __restrict__ PWe1m,
    unsigned short* __restrict__ PWe2, unsigned short* __restrict__ PWx1,
    unsigned short* __restrict__ PWh1, unsigned short* __restrict__ PWh2,
    int* __restrict__ cnt)
{
    const size_t NH4 = (size_t)NN * HD / 4;
    const size_t Z1 = ZDW, C1 = Z1 + NH4;
    const size_t T1 = C1 + S_PWT, T2 = T1 + S_PWE1M, T3 = T2 + S_PW4;
    const size_t T4 = T3 + S_PW4, T5 = T4 + S_PWH1, T6 = T5 + S_PWH2;
    const size_t TOT = T6 + NE;
    const size_t stride = (size_t)gridDim.x * blockDim.x;
    for (size_t i = (size_t)blockIdx.x * blockDim.x + threadIdx.x; i < TOT; i += stride) {
        if (i < Z1) { zbase[i] = 0; continue; }
        if (i < C1) {
            const size_t r = i - Z1;
            const float4 v = ((const float4*)h)[r];
            unsigned* dst = (unsigned*)&hb[r * 4];
            dst[0] = pack2bf(v.x, v.y);
            dst[1] = pack2bf(v.z, v.w);
            continue;
        }
        if (i < T1) {   // We1 tail (rows 256..272), i8 cols, kb==0
            const int idx = (int)(i - C1);
            const int r = idx & 511, nb = idx >> 9;
            const int lane = r >> 3, j = r & 7;
            const int k = 256 + (lane >> 4) * 8 + j;
            const int n = 8 * (lane & 15) + nb;
            PWt[idx] = f2bf((k < KIN) ? We1[(size_t)k * HD + n] : 0.0f);
            continue;
        }
        if (i < T2) { pack_il(We1, 256, PWe1m, (int)(i - T1)); continue; }
        if (i < T3) { pack_i8(We2, HD, PWe2, (int)(i - T2)); continue; }
        if (i < T4) { pack_i8(Wx1, HD, PWx1, (int)(i - T3)); continue; }
        if (i < T5) { pack_id(Wh1, 2 * HD, PWh1, (int)(i - T4)); continue; }
        if (i < T6) { pack_id(Wh2, HD, PWh2, (int)(i - T5)); continue; }
        atomicAdd(&cnt[ei[NE + (i - T6)]], 1);
    }
}

// ============ preGEMM (blocks 0..312) + scan (block 313) — unchanged =======
__global__ __launch_bounds__(256, 4) void egnn_pre_kernel(
    const unsigned short* __restrict__ hb,
    const unsigned short* __restrict__ PWe1m, const float* __restrict__ be1,
    const int* __restrict__ cnt, int* __restrict__ cursor,
    unsigned short* __restrict__ preS, unsigned short* __restrict__ preD)
{
    const int t = threadIdx.x;
    if (blockIdx.x == 313) {
        __shared__ int ls[256];
        const int base = t * 79;
        int c[79];
        int s = 0;
        for (int i = 0; i < 79; ++i) {
            const int idx = base + i;
            c[i] = (idx < NN) ? cnt[idx] : 0;
            s += c[i];
        }
        ls[t] = s;
        __syncthreads();
        int v = s;
        for (int off = 1; off < 256; off <<= 1) {
            const int u = (t >= off) ? ls[t - off] : 0;
            __syncthreads();
            v += u;
            ls[t] = v;
            __syncthreads();
        }
        int run = v - s;
        for (int i = 0; i < 79; ++i) {
            const int idx = base + i;
            if (idx < NN) { cursor[idx] = run; run += c[i]; }
        }
        return;
    }
    const int n0 = blockIdx.x * 64;
    const int lane = t & 63, w = t >> 6;
    const int quad = lane >> 4, l16 = lane & 15;
    int arow[4];
    #pragma unroll
    for (int mb = 0; mb < 4; ++mb) arow[mb] = min(n0 + mb * 16 + l16, NN - 1);

    f32x4 accS[4][2], accD[4][2];
    #pragma unroll
    for (int mb = 0; mb < 4; ++mb)
        #pragma unroll
        for (int nt = 0; nt < 2; ++nt) {
            accS[mb][nt] = (f32x4){0.f,0.f,0.f,0.f};
            accD[mb][nt] = (f32x4){0.f,0.f,0.f,0.f};
        }
    #pragma unroll
    for (int kb = 0; kb < 4; ++kb) {
        bf16x8 a[4], bS[2], bD[2];
        #pragma unroll
        for (int mb = 0; mb < 4; ++mb)
            a[mb] = *(const bf16x8*)&hb[(size_t)arow[mb] * HD + kb * 32 + quad * 8];
        #pragma unroll
        for (int nt = 0; nt < 2; ++nt) {
            bS[nt] = *(const bf16x8*)&PWe1m[((kb * 8 + w * 2 + nt) * 64 + lane) * 8];
            bD[nt] = *(const bf16x8*)&PWe1m[(((4 + kb) * 8 + w * 2 + nt) * 64 + lane) * 8];
        }
        #pragma unroll
        for (int mb = 0; mb < 4; ++mb)
            #pragma unroll
            for (int nt = 0; nt < 2; ++nt) {
                accS[mb][nt] = __builtin_amdgcn_mfma_f32_16x16x32_bf16(
                    a[mb], bS[nt], accS[mb][nt], 0, 0, 0);
                accD[mb][nt] = __builtin_amdgcn_mfma_f32_16x16x32_bf16(
                    a[mb], bD[nt], accD[mb][nt], 0, 0, 0);
            }
    }
    const int cb = w * 32 + 2 * l16;
    const float2 b1 = *(const float2*)&be1[cb];
    #pragma unroll
    for (int mb = 0; mb < 4; ++mb)
        #pragma unroll
        for (int r = 0; r < 4; ++r) {
            const int n = n0 + mb * 16 + quad * 4 + r;
            if (n < NN) {
                *(unsigned*)&preS[(size_t)n * HD + cb] =
                    pack2bf(accS[mb][0][r], accS[mb][1][r]);
                *(unsigned*)&preD[(size_t)n * HD + cb] =
                    pack2bf(accD[mb][0][r] + b1.x, accD[mb][1][r] + b1.y);
            }
        }
}

// ============ perm (unchanged) ============
__global__ void egnn_perm_kernel(const int* __restrict__ ei,
                                 int* __restrict__ cursor, int* __restrict__ perm) {
    const int e = blockIdx.x * 256 + threadIdx.x;
    const int pos = atomicAdd(&cursor[ei[NE + e]], 1);
    perm[pos] = e;
}

// ===== edge kernel: 16-rows-per-wave decomposition, 8 adjacent cols/thread ==
__global__ __launch_bounds__(256, 6) void egnn_edge_kernel(
    const unsigned short* __restrict__ preS, const unsigned short* __restrict__ preD,
    const float* __restrict__ x,
    const int* __restrict__ ei, const float* __restrict__ eattr,
    const int* __restrict__ perm,
    const unsigned short* __restrict__ PWt,
    const unsigned short* __restrict__ PWe2, const float* __restrict__ be2,
    const unsigned short* __restrict__ PWx1, const float* __restrict__ bx1,
    const float* __restrict__ Wx2, const float* __restrict__ bx2,
    float* __restrict__ msg_agg, float* __restrict__ coord_agg)
{
    __shared__ __align__(16) unsigned short buf[64 * P2];   // tail -> sT -> sM
    __shared__ int   sE[64], sSrc[64], sDst[64];
    __shared__ float sDiff[64][3];
    __shared__ float sW[64];

    const int t  = threadIdx.x;
    const int e0 = blockIdx.x * 64;
    unsigned short* tail = buf;   // [64][32]

    if (t < 64) {
        const int e = perm[e0 + t];
        sE[t] = e;
        const int s = ei[e];
        const int d = ei[NE + e];
        sSrc[t] = s; sDst[t] = d;
        const float dx = x[s*3+0] - x[d*3+0];
        const float dy = x[s*3+1] - x[d*3+1];
        const float dz = x[s*3+2] - x[d*3+2];
        sDiff[t][0] = dx; sDiff[t][1] = dy; sDiff[t][2] = dz;
        tail[t * 32 + 0] = f2bf((dx*dx + dy*dy + dz*dz) * 0.01f);
    }
    __syncthreads();

    const int lane = t & 63;
    const int w    = t >> 6;
    const int quad = lane >> 4;
    const int l16  = lane & 15;
    const int c8   = 8 * l16;        // thread's 8 adjacent logical cols
    int rowg[4];
    #pragma unroll
    for (int r = 0; r < 4; ++r) rowg[r] = w * 16 + quad * 4 + r;

    // acc init = preS[src] + preD[dst] (preD includes be1); b128 loads
    f32x4 acc[8];
    #pragma unroll
    for (int r = 0; r < 4; ++r) {
        const int row = rowg[r];
        const uint4 us = *(const uint4*)&preS[(size_t)sSrc[row] * HD + c8];
        const uint4 ud = *(const uint4*)&preD[(size_t)sDst[row] * HD + c8];
        acc[0][r] = lo16(us.x) + lo16(ud.x);  acc[1][r] = hi16(us.x) + hi16(ud.x);
        acc[2][r] = lo16(us.y) + lo16(ud.y);  acc[3][r] = hi16(us.y) + hi16(ud.y);
        acc[4][r] = lo16(us.z) + lo16(ud.z);  acc[5][r] = hi16(us.z) + hi16(ud.z);
        acc[6][r] = lo16(us.w) + lo16(ud.w);  acc[7][r] = hi16(us.w) + hi16(ud.w);
    }

    // tail cols 1..31
    {
        const int eL = t >> 2, q = t & 3;
        const int eG = sE[eL];
        #pragma unroll
        for (int jj = 0; jj < 8; ++jj) {
            const int col = q * 8 + jj;
            if (col == 0) continue;
            float v = 0.0f;
            if (col <= EDIM) v = eattr[(size_t)eG * EDIM + (col - 1)];
            tail[eL * 32 + col] = f2bf(v);
        }
    }
    __syncthreads();

    // GEMM1 (K=32 tail), acc += tail @ PWt
    {
        const bf16x8 a = *(const bf16x8*)&tail[(w * 16 + l16) * 32 + quad * 8];
        #pragma unroll
        for (int nt = 0; nt < 8; ++nt) {
            const bf16x8 b = *(const bf16x8*)&PWt[(nt * 64 + lane) * 8];
            acc[nt] = __builtin_amdgcn_mfma_f32_16x16x32_bf16(a, b, acc[nt], 0, 0, 0);
        }
    }
    __syncthreads();   // tail reads done -> buf reusable as sT

    // sT = silu(acc), b128 stores
    #pragma unroll
    for (int r = 0; r < 4; ++r) {
        uint4 o;
        o.x = pack2bf(silu_f(acc[0][r]), silu_f(acc[1][r]));
        o.y = pack2bf(silu_f(acc[2][r]), silu_f(acc[3][r]));
        o.z = pack2bf(silu_f(acc[4][r]), silu_f(acc[5][r]));
        o.w = pack2bf(silu_f(acc[6][r]), silu_f(acc[7][r]));
        *(uint4*)&buf[rowg[r] * P2 + c8] = o;
    }
    __syncthreads();

    // GEMM2: sT @ We2
    #pragma unroll
    for (int nt = 0; nt < 8; ++nt) acc[nt] = (f32x4){0.f,0.f,0.f,0.f};
    #pragma unroll
    for (int kb = 0; kb < 4; ++kb) {
        const bf16x8 a = *(const bf16x8*)&buf[(w * 16 + l16) * P2 + kb * 32 + quad * 8];
        #pragma unroll
        for (int nt = 0; nt < 8; ++nt) {
            const bf16x8 b = *(const bf16x8*)&PWe2[((kb * 8 + nt) * 64 + lane) * 8];
            acc[nt] = __builtin_amdgcn_mfma_f32_16x16x32_bf16(a, b, acc[nt], 0, 0, 0);
        }
    }
    __syncthreads();   // sT reads done -> buf reusable as sM

    // sM = silu(acc + be2)
    {
        const float4 ba = *(const float4*)&be2[c8];
        const float4 bb = *(const float4*)&be2[c8 + 4];
        #pragma unroll
        for (int r = 0; r < 4; ++r) {
            uint4 o;
            o.x = pack2bf(silu_f(acc[0][r] + ba.x), silu_f(acc[1][r] + ba.y));
            o.y = pack2bf(silu_f(acc[2][r] + ba.z), silu_f(acc[3][r] + ba.w));
            o.z = pack2bf(silu_f(acc[4][r] + bb.x), silu_f(acc[5][r] + bb.y));
            o.w = pack2bf(silu_f(acc[6][r] + bb.z), silu_f(acc[7][r] + bb.w));
            *(uint4*)&buf[rowg[r] * P2 + c8] = o;
        }
    }
    __syncthreads();

    // msg: dst-sorted run reduction (natural col order)
    {
        const int cp = t & 63;
        const int r0 = (t >> 6) * 16;
        float a0 = 0.0f, a1 = 0.0f;
        #pragma unroll 4
        for (int r = 0; r < 16; ++r) {
            const int row = r0 + r;
            const int d   = sDst[row];
            const unsigned u = *(const unsigned*)&buf[row * P2 + 2 * cp];
            a0 += lo16(u);
            a1 += hi16(u);
            const bool flush = (r == 15) || (sDst[row + 1] != d);
            if (flush) {
                atomicAdd(&msg_agg[(size_t)d * HD + 2 * cp], a0);
                atomicAdd(&msg_agg[(size_t)d * HD + 2 * cp + 1], a1);
                a0 = 0.0f; a1 = 0.0f;
            }
        }
    }

    // GEMM3: sM @ Wx1
    #pragma unroll
    for (int nt = 0; nt < 8; ++nt) acc[nt] = (f32x4){0.f,0.f,0.f,0.f};
    #pragma unroll
    for (int kb = 0; kb < 4; ++kb) {
        const bf16x8 a = *(const bf16x8*)&buf[(w * 16 + l16) * P2 + kb * 32 + quad * 8];
        #pragma unroll
        for (int nt = 0; nt < 8; ++nt) {
            const bf16x8 b = *(const bf16x8*)&PWx1[((kb * 8 + nt) * 64 + lane) * 8];
            acc[nt] = __builtin_amdgcn_mfma_f32_16x16x32_bf16(a, b, acc[nt], 0, 0, 0);
        }
    }
    // coord_w: per-thread 8-col partial, shfl over l16, in-wave tanh -> sW
    {
        const float4 ba = *(const float4*)&bx1[c8];
        const float4 bb = *(const float4*)&bx1[c8 + 4];
        const float4 wa = *(const float4*)&Wx2[c8];
        const float4 wb = *(const float4*)&Wx2[c8 + 4];
        float p[4];
        #pragma unroll
        for (int r = 0; r < 4; ++r) {
            p[r] = silu_f(acc[0][r] + ba.x) * wa.x + silu_f(acc[1][r] + ba.y) * wa.y
                 + silu_f(acc[2][r] + ba.z) * wa.z + silu_f(acc[3][r] + ba.w) * wa.w
                 + silu_f(acc[4][r] + bb.x) * wb.x + silu_f(acc[5][r] + bb.y) * wb.y
                 + silu_f(acc[6][r] + bb.z) * wb.z + silu_f(acc[7][r] + bb.w) * wb.w;
        }
        #pragma unroll
        for (int off = 8; off >= 1; off >>= 1)
            #pragma unroll
            for (int r = 0; r < 4; ++r)
                p[r] += __shfl_xor(p[r], off, 64);
        if (l16 == 0) {
            #pragma unroll
            for (int r = 0; r < 4; ++r)
                sW[rowg[r]] = tanh_f(p[r] + bx2[0]);
        }
    }
    __syncthreads();

    // coord: per-wave segmented shuffle reduction (dst-sorted)
    if (w < 3) {
        const int dstv = sDst[lane];
        float v = sDiff[lane][w] * sW[lane];
        #pragma unroll
        for (int off = 1; off <= 32; off <<= 1) {
            const int   dn = __shfl_down(dstv, off, 64);
            const float vn = __shfl_down(v, off, 64);
            if (lane + off < 64 && dn == dstv) v += vn;
        }
        const int up = __shfl_up(dstv, 1, 64);
        if (lane == 0 || up != dstv)
            atomicAdd(&coord_agg[(size_t)dstv * 3 + w], v);
    }
}

// ============ node kernel (unchanged) ============
__global__ __launch_bounds__(256, 4) void egnn_node_kernel(
    const unsigned short* __restrict__ hb, const float* __restrict__ h,
    const float* __restrict__ x, const int* __restrict__ fixed_mask,
    const unsigned short* __restrict__ PWh1, const float* __restrict__ bh1,
    const unsigned short* __restrict__ PWh2, const float* __restrict__ bh2,
    const float* __restrict__ msg_agg, const float* __restrict__ coord_agg,
    float* __restrict__ out_h, float* __restrict__ out_x)
{
    __shared__ __align__(16) unsigned short sTn[64 * P2];
    const int t  = threadIdx.x;
    const int n0 = blockIdx.x * 64;
    const int lane = t & 63, w = t >> 6;
    const int quad = lane >> 4, l16 = lane & 15;

    if (t < 192) {
        const int ln = t / 3, d3 = t - ln * 3;
        const int n  = n0 + ln;
        if (n < NN) {
            const float add = (fixed_mask[n] != 0) ? 0.0f : coord_agg[(size_t)n*3 + d3];
            out_x[(size_t)n*3 + d3] = x[(size_t)n*3 + d3] + add;
        }
    }

    int nrow[4];
    #pragma unroll
    for (int mb = 0; mb < 4; ++mb) nrow[mb] = min(n0 + mb * 16 + l16, NN - 1);

    f32x4 acc[4][2];
    #pragma unroll
    for (int mb = 0; mb < 4; ++mb)
        #pragma unroll
        for (int nt = 0; nt < 2; ++nt) acc[mb][nt] = (f32x4){0.f,0.f,0.f,0.f};

    #pragma unroll
    for (int kb = 0; kb < 8; ++kb) {
        bf16x8 a[4], b[2];
        if (kb < 4) {
            #pragma unroll
            for (int mb = 0; mb < 4; ++mb)
                a[mb] = *(const bf16x8*)&hb[(size_t)nrow[mb] * HD + kb * 32 + quad * 8];
        } else {
            #pragma unroll
            for (int mb = 0; mb < 4; ++mb) {
                const float* mp = msg_agg + (size_t)nrow[mb] * HD + (kb - 4) * 32 + quad * 8;
                const float4 v0 = ((const float4*)mp)[0];
                const float4 v1 = ((const float4*)mp)[1];
                bf16x8 av;
                av[0]=(__bf16)v0.x; av[1]=(__bf16)v0.y; av[2]=(__bf16)v0.z; av[3]=(__bf16)v0.w;
                av[4]=(__bf16)v1.x; av[5]=(__bf16)v1.y; av[6]=(__bf16)v1.z; av[7]=(__bf16)v1.w;
                a[mb] = av;
            }
        }
        #pragma unroll
        for (int nt = 0; nt < 2; ++nt)
            b[nt] = *(const bf16x8*)&PWh1[((kb * 8 + w * 2 + nt) * 64 + lane) * 8];
        #pragma unroll
        for (int mb = 0; mb < 4; ++mb)
            #pragma unroll
            for (int nt = 0; nt < 2; ++nt)
                acc[mb][nt] = __builtin_amdgcn_mfma_f32_16x16x32_bf16(
                    a[mb], b[nt], acc[mb][nt], 0, 0, 0);
    }
    #pragma unroll
    for (int nt = 0; nt < 2; ++nt) {
        const int col = w * 32 + nt * 16 + l16;
        const float bias = bh1[col];
        #pragma unroll
        for (int mb = 0; mb < 4; ++mb)
            #pragma unroll
            for (int r = 0; r < 4; ++r) {
                const int row = mb * 16 + quad * 4 + r;
                sTn[row * P2 + col] = f2bf(silu_f(acc[mb][nt][r] + bias));
            }
    }
    __syncthreads();

    #pragma unroll
    for (int mb = 0; mb < 4; ++mb)
        #pragma unroll
        for (int nt = 0; nt < 2; ++nt) acc[mb][nt] = (f32x4){0.f,0.f,0.f,0.f};
    #pragma unroll
    for (int kb = 0; kb < 4; ++kb) {
        bf16x8 a[4], b[2];
        #pragma unroll
        for (int mb = 0; mb < 4; ++mb)
            a[mb] = *(const bf16x8*)&sTn[(mb * 16 + l16) * P2 + kb * 32 + quad * 8];
        #pragma unroll
        for (int nt = 0; nt < 2; ++nt)
            b[nt] = *(const bf16x8*)&PWh2[((kb * 8 + w * 2 + nt) * 64 + lane) * 8];
        #pragma unroll
        for (int mb = 0; mb < 4; ++mb)
            #pragma unroll
            for (int nt = 0; nt < 2; ++nt)
                acc[mb][nt] = __builtin_amdgcn_mfma_f32_16x16x32_bf16(
                    a[mb], b[nt], acc[mb][nt], 0, 0, 0);
    }
    #pragma unroll
    for (int nt = 0; nt < 2; ++nt) {
        const int col = w * 32 + nt * 16 + l16;
        const float bias = bh2[col];
        #pragma unroll
        for (int mb = 0; mb < 4; ++mb)
            #pragma unroll
            for (int r = 0; r < 4; ++r) {
                const int row = mb * 16 + quad * 4 + r;
                const int n   = n0 + row;
                if (n < NN)
                    out_h[(size_t)n * HD + col] =
                        h[(size_t)n * HD + col] + acc[mb][nt][r] + bias;
            }
    }
}

extern "C" void kernel_launch(void* const* d_in, const int* in_sizes, int n_in,
                              void* d_out, int out_size, void* d_ws, size_t ws_size,
                              hipStream_t stream)
{
    const float* h     = (const float*)d_in[0];
    const float* x     = (const float*)d_in[1];
    const int*   ei    = (const int*)d_in[2];
    const float* eattr = (const float*)d_in[3];
    const int*   fmask = (const int*)d_in[4];
    const float* We1   = (const float*)d_in[5];
    const float* be1   = (const float*)d_in[6];
    const float* We2   = (const float*)d_in[7];
    const float* be2   = (const float*)d_in[8];
    const float* Wx1   = (const float*)d_in[9];
    const float* bx1   = (const float*)d_in[10];
    const float* Wx2   = (const float*)d_in[11];
    const float* bx2   = (const float*)d_in[12];
    const float* Wh1   = (const float*)d_in[13];
    const float* bh1   = (const float*)d_in[14];
    const float* Wh2   = (const float*)d_in[15];
    const float* bh2   = (const float*)d_in[16];

    float* msg    = (float*)d_ws;                        // NN*HD (zeroed by prep)
    float* coord  = msg + (size_t)NN * HD;               // NN*3  (zeroed by prep)
    int*   cnt    = (int*)(coord + (size_t)NN * 3);      // NN    (zeroed by memset)
    int*   cursor = cnt + NN;                            // NN
    int*   perm   = cursor + NN;                         // NE
    unsigned short* hb    = (unsigned short*)(perm + NE);
    unsigned short* preS  = hb + (size_t)NN * HD;
    unsigned short* preD  = preS + (size_t)NN * HD;
    unsigned short* PWt   = preD + (size_t)NN * HD;
    unsigned short* PWe1m = PWt + S_PWT;
    unsigned short* PWe2  = PWe1m + S_PWE1M;
    unsigned short* PWx1  = PWe2 + S_PW4;
    unsigned short* PWh1  = PWx1 + S_PW4;
    unsigned short* PWh2  = PWh1 + S_PWH1;

    float* out_h = (float*)d_out;
    float* out_x = out_h + (size_t)NN * HD;

    hipMemsetAsync(cnt, 0, (size_t)NN * sizeof(int), stream);
    egnn_prep_kernel<<<1024, 256, 0, stream>>>(
        h, ei, We1, We2, Wx1, Wh1, Wh2, (int*)d_ws,
        hb, PWt, PWe1m, PWe2, PWx1, PWh1, PWh2, cnt);
    egnn_pre_kernel<<<314, 256, 0, stream>>>(hb, PWe1m, be1, cnt, cursor, preS, preD);
    egnn_perm_kernel<<<NE / 256, 256, 0, stream>>>(ei, cursor, perm);
    egnn_edge_kernel<<<NE / 64, 256, 0, stream>>>(
        preS, preD, x, ei, eattr, perm, PWt, PWe2, be2, PWx1, bx1,
        Wx2, bx2, msg, coord);
    egnn_node_kernel<<<(NN + 63) / 64, 256, 0, stream>>>(
        hb, h, x, fmask, PWh1, bh1, PWh2, bh2, msg, coord, out_h, out_x);
}

// Round 16
// 379.229 us; speedup vs baseline: 1.3090x; 1.3090x over previous
//
#include <hip/hip_runtime.h>
#include <hip/hip_bf16.h>
#include <math.h>

#define NN   20000
#define NE   640000
#define HD   128
#define EDIM 16
#define KIN  273
#define P2   136      // LDS pitch (ushorts)

#define S_PWT   4096    // We1 tail:   1 kb x 8 nb x 512 (interleaved cols)
#define S_PWE1M 32768   // We1 main:   8 kb x 8 nb x 512 (interleaved cols)
#define S_PW4   16384   // We2/Wx1:    4 kb x 8 nb x 512 (interleaved cols)
#define S_PWH1  32768   // Wh1:        8 kb x 8 nb x 512 (identity cols)
#define S_PWH2  16384   // Wh2:        4 kb x 8 nb x 512 (identity cols)

typedef __bf16 bf16x8 __attribute__((ext_vector_type(8)));
typedef float  f32x4  __attribute__((ext_vector_type(4)));

__device__ __forceinline__ float silu_f(float v) {
    const float e = __expf(-v);
    return v * __builtin_amdgcn_rcpf(1.0f + e);
}
__device__ __forceinline__ float tanh_f(float s) {
    const float e = __expf(2.0f * s);
    return 1.0f - 2.0f * __builtin_amdgcn_rcpf(e + 1.0f);
}
__device__ __forceinline__ unsigned short f2bf(float f) {
    __bf16 b = (__bf16)f;
    return __builtin_bit_cast(unsigned short, b);
}
__device__ __forceinline__ float bf2f(unsigned short u) {
    __bf16 b = __builtin_bit_cast(__bf16, u);
    return (float)b;
}
__device__ __forceinline__ unsigned pack2bf(float a, float b) {
    return (unsigned)f2bf(a) | ((unsigned)f2bf(b) << 16);
}

// identity pack: tile (kb,nb): elem[lane*8+j] = W[kb*32+(lane>>4)*8+j][nb*16+(lane&15)]
__device__ __forceinline__ void pack_id(const float* __restrict__ W, int Kreal,
                                        unsigned short* __restrict__ P, int idx) {
    const int f = idx >> 9, r = idx & 511;
    const int lane = r >> 3, j = r & 7;
    const int kb = f >> 3, nb = f & 7;
    const int k = kb * 32 + (lane >> 4) * 8 + j;
    const int n = nb * 16 + (lane & 15);
    P[idx] = f2bf((k < Kreal) ? W[(size_t)k * HD + n] : 0.0f);
}
// interleaved pack: n = (nb>>1)*32 + 2*(lane&15) + (nb&1)
__device__ __forceinline__ void pack_il(const float* __restrict__ W, int Kreal,
                                        unsigned short* __restrict__ P, int idx) {
    const int f = idx >> 9, r = idx & 511;
    const int lane = r >> 3, j = r & 7;
    const int kb = f >> 3, nb = f & 7;
    const int k = kb * 32 + (lane >> 4) * 8 + j;
    const int n = (nb >> 1) * 32 + 2 * (lane & 15) + (nb & 1);
    P[idx] = f2bf((k < Kreal) ? W[(size_t)k * HD + n] : 0.0f);
}

// ===== prep: zero msg/coord + cast h + pack all weights + dst histogram =====
#define ZDW (NN*(HD+3))   // msg|coord dwords (cnt zeroed by the tiny memset)

__global__ void egnn_prep_kernel(
    const float* __restrict__ h, const int* __restrict__ ei,
    const float* __restrict__ We1, const float* __restrict__ We2,
    const float* __restrict__ Wx1, const float* __restrict__ Wh1,
    const float* __restrict__ Wh2,
    int* __restrict__ zbase,
    unsigned short* __restrict__ hb,
    unsigned short* __restrict__ PWt,  unsigned short* __restrict__ PWe1m,
    unsigned short* __restrict__ PWe2, unsigned short* __restrict__ PWx1,
    unsigned short* __restrict__ PWh1, unsigned short* __restrict__ PWh2,
    int* __restrict__ cnt)
{
    const size_t NH4 = (size_t)NN * HD / 4;   // h cast in float4 units
    const size_t Z1 = ZDW, C1 = Z1 + NH4;
    const size_t T1 = C1 + S_PWT, T2 = T1 + S_PWE1M, T3 = T2 + S_PW4;
    const size_t T4 = T3 + S_PW4, T5 = T4 + S_PWH1, T6 = T5 + S_PWH2;
    const size_t TOT = T6 + NE;
    const size_t stride = (size_t)gridDim.x * blockDim.x;
    for (size_t i = (size_t)blockIdx.x * blockDim.x + threadIdx.x; i < TOT; i += stride) {
        if (i < Z1) { zbase[i] = 0; continue; }
        if (i < C1) {
            const size_t r = i - Z1;
            const float4 v = ((const float4*)h)[r];
            unsigned* dst = (unsigned*)&hb[r * 4];
            dst[0] = pack2bf(v.x, v.y);
            dst[1] = pack2bf(v.z, v.w);
            continue;
        }
        if (i < T1) {   // We1 tail (rows 256..272), interleaved cols, kb==0
            const int idx = (int)(i - C1);
            const int r = idx & 511, nb = idx >> 9;
            const int lane = r >> 3, j = r & 7;
            const int k = 256 + (lane >> 4) * 8 + j;
            const int n = (nb >> 1) * 32 + 2 * (lane & 15) + (nb & 1);
            PWt[idx] = f2bf((k < KIN) ? We1[(size_t)k * HD + n] : 0.0f);
            continue;
        }
        if (i < T2) { pack_il(We1, 256, PWe1m, (int)(i - T1)); continue; }
        if (i < T3) { pack_il(We2, HD, PWe2, (int)(i - T2)); continue; }
        if (i < T4) { pack_il(Wx1, HD, PWx1, (int)(i - T3)); continue; }
        if (i < T5) { pack_id(Wh1, 2 * HD, PWh1, (int)(i - T4)); continue; }
        if (i < T6) { pack_id(Wh2, HD, PWh2, (int)(i - T5)); continue; }
        atomicAdd(&cnt[ei[NE + (i - T6)]], 1);   // histogram
    }
}

// ============ preGEMM (blocks 0..312) + scan (block 313) ============
__global__ __launch_bounds__(256, 4) void egnn_pre_kernel(
    const unsigned short* __restrict__ hb,
    const unsigned short* __restrict__ PWe1m, const float* __restrict__ be1,
    const int* __restrict__ cnt, int* __restrict__ cursor,
    unsigned short* __restrict__ preS, unsigned short* __restrict__ preD)
{
    const int t = threadIdx.x;
    if (blockIdx.x == 313) {        // exclusive scan of cnt -> cursor (SEG=79)
        __shared__ int ls[256];
        const int base = t * 79;
        int c[79];
        int s = 0;
        for (int i = 0; i < 79; ++i) {
            const int idx = base + i;
            c[i] = (idx < NN) ? cnt[idx] : 0;
            s += c[i];
        }
        ls[t] = s;
        __syncthreads();
        int v = s;
        for (int off = 1; off < 256; off <<= 1) {
            const int u = (t >= off) ? ls[t - off] : 0;
            __syncthreads();
            v += u;
            ls[t] = v;
            __syncthreads();
        }
        int run = v - s;
        for (int i = 0; i < 79; ++i) {
            const int idx = base + i;
            if (idx < NN) { cursor[idx] = run; run += c[i]; }
        }
        return;
    }
    // preS = h@We1[0:128]; preD = h@We1[128:256] + be1 (interleaved col order)
    const int n0 = blockIdx.x * 64;
    const int lane = t & 63, w = t >> 6;
    const int quad = lane >> 4, l16 = lane & 15;
    int arow[4];
    #pragma unroll
    for (int mb = 0; mb < 4; ++mb) arow[mb] = min(n0 + mb * 16 + l16, NN - 1);

    f32x4 accS[4][2], accD[4][2];
    #pragma unroll
    for (int mb = 0; mb < 4; ++mb)
        #pragma unroll
        for (int nt = 0; nt < 2; ++nt) {
            accS[mb][nt] = (f32x4){0.f,0.f,0.f,0.f};
            accD[mb][nt] = (f32x4){0.f,0.f,0.f,0.f};
        }
    #pragma unroll
    for (int kb = 0; kb < 4; ++kb) {
        bf16x8 a[4], bS[2], bD[2];
        #pragma unroll
        for (int mb = 0; mb < 4; ++mb)
            a[mb] = *(const bf16x8*)&hb[(size_t)arow[mb] * HD + kb * 32 + quad * 8];
        #pragma unroll
        for (int nt = 0; nt < 2; ++nt) {
            bS[nt] = *(const bf16x8*)&PWe1m[((kb * 8 + w * 2 + nt) * 64 + lane) * 8];
            bD[nt] = *(const bf16x8*)&PWe1m[(((4 + kb) * 8 + w * 2 + nt) * 64 + lane) * 8];
        }
        #pragma unroll
        for (int mb = 0; mb < 4; ++mb)
            #pragma unroll
            for (int nt = 0; nt < 2; ++nt) {
                accS[mb][nt] = __builtin_amdgcn_mfma_f32_16x16x32_bf16(
                    a[mb], bS[nt], accS[mb][nt], 0, 0, 0);
                accD[mb][nt] = __builtin_amdgcn_mfma_f32_16x16x32_bf16(
                    a[mb], bD[nt], accD[mb][nt], 0, 0, 0);
            }
    }
    const int cb = w * 32 + 2 * l16;
    const float2 b1 = *(const float2*)&be1[cb];
    #pragma unroll
    for (int mb = 0; mb < 4; ++mb)
        #pragma unroll
        for (int r = 0; r < 4; ++r) {
            const int n = n0 + mb * 16 + quad * 4 + r;
            if (n < NN) {
                *(unsigned*)&preS[(size_t)n * HD + cb] =
                    pack2bf(accS[mb][0][r], accS[mb][1][r]);
                *(unsigned*)&preD[(size_t)n * HD + cb] =
                    pack2bf(accD[mb][0][r] + b1.x, accD[mb][1][r] + b1.y);
            }
        }
}

// ============ perm ============
__global__ void egnn_perm_kernel(const int* __restrict__ ei,
                                 int* __restrict__ cursor, int* __restrict__ perm) {
    const int e = blockIdx.x * 256 + threadIdx.x;
    const int pos = atomicAdd(&cursor[ei[NE + e]], 1);
    perm[pos] = e;
}

// ===== edge kernel: single phase-shared LDS buffer, 6 blocks/CU (no spill) =====
__global__ __launch_bounds__(256, 6) void egnn_edge_kernel(
    const unsigned short* __restrict__ preS, const unsigned short* __restrict__ preD,
    const float* __restrict__ x,
    const int* __restrict__ ei, const float* __restrict__ eattr,
    const int* __restrict__ perm,
    const unsigned short* __restrict__ PWt,
    const unsigned short* __restrict__ PWe2, const float* __restrict__ be2,
    const unsigned short* __restrict__ PWx1, const float* __restrict__ bx1,
    const float* __restrict__ Wx2, const float* __restrict__ bx2,
    float* __restrict__ msg_agg, float* __restrict__ coord_agg)
{
    __shared__ __align__(16) unsigned short buf[64 * P2];   // tail -> sT -> sM -> red
    __shared__ int   sE[64], sSrc[64], sDst[64];
    __shared__ float sDiff[64][3];
    __shared__ float sW[64];

    const int t  = threadIdx.x;
    const int e0 = blockIdx.x * 64;
    unsigned short* tail = buf;   // [64][32] in first 4 KB

    if (t < 64) {
        const int e = perm[e0 + t];
        sE[t] = e;
        const int s = ei[e];
        const int d = ei[NE + e];
        sSrc[t] = s; sDst[t] = d;
        const float dx = x[s*3+0] - x[d*3+0];
        const float dy = x[s*3+1] - x[d*3+1];
        const float dz = x[s*3+2] - x[d*3+2];
        sDiff[t][0] = dx; sDiff[t][1] = dy; sDiff[t][2] = dz;
        tail[t * 32 + 0] = f2bf((dx*dx + dy*dy + dz*dz) * 0.01f);
    }
    __syncthreads();

    const int lane = t & 63;
    const int w    = t >> 6;
    const int quad = lane >> 4;
    const int l16  = lane & 15;
    const int cb   = w * 32 + 2 * l16;

    // preC = preS[src] + preD[dst] (preD includes be1)
    f32x4 preC[4][2];
    #pragma unroll
    for (int mb = 0; mb < 4; ++mb)
        #pragma unroll
        for (int r = 0; r < 4; ++r) {
            const int row = mb * 16 + quad * 4 + r;
            const unsigned us = *(const unsigned*)&preS[(size_t)sSrc[row] * HD + cb];
            const unsigned ud = *(const unsigned*)&preD[(size_t)sDst[row] * HD + cb];
            preC[mb][0][r] = bf2f((unsigned short)(us & 0xffff)) +
                             bf2f((unsigned short)(ud & 0xffff));
            preC[mb][1][r] = bf2f((unsigned short)(us >> 16)) +
                             bf2f((unsigned short)(ud >> 16));
        }

    // tail cols 1..31
    {
        const int eL = t >> 2, q = t & 3;
        const int eG = sE[eL];
        #pragma unroll
        for (int jj = 0; jj < 8; ++jj) {
            const int col = q * 8 + jj;
            if (col == 0) continue;
            float v = 0.0f;
            if (col <= EDIM) v = eattr[(size_t)eG * EDIM + (col - 1)];
            tail[eL * 32 + col] = f2bf(v);
        }
    }
    __syncthreads();

    // GEMM1 (K=32 tail), C init = preC
    f32x4 acc1[4][2];
    {
        bf16x8 a[4], b[2];
        #pragma unroll
        for (int mb = 0; mb < 4; ++mb)
            a[mb] = *(const bf16x8*)&tail[(mb * 16 + l16) * 32 + quad * 8];
        #pragma unroll
        for (int nt = 0; nt < 2; ++nt)
            b[nt] = *(const bf16x8*)&PWt[((w * 2 + nt) * 64 + lane) * 8];
        #pragma unroll
        for (int mb = 0; mb < 4; ++mb)
            #pragma unroll
            for (int nt = 0; nt < 2; ++nt)
                acc1[mb][nt] = __builtin_amdgcn_mfma_f32_16x16x32_bf16(
                    a[mb], b[nt], preC[mb][nt], 0, 0, 0);
    }
    __syncthreads();   // all tail reads done -> buf reusable as sT

    #pragma unroll
    for (int mb = 0; mb < 4; ++mb)
        #pragma unroll
        for (int r = 0; r < 4; ++r) {
            const int row = mb * 16 + quad * 4 + r;
            *(unsigned*)&buf[row * P2 + cb] =
                pack2bf(silu_f(acc1[mb][0][r]), silu_f(acc1[mb][1][r]));
        }
    __syncthreads();

    // GEMM2: t1 @ We2
    f32x4 acc2[4][2];
    #pragma unroll
    for (int mb = 0; mb < 4; ++mb)
        #pragma unroll
        for (int nt = 0; nt < 2; ++nt) acc2[mb][nt] = (f32x4){0.f,0.f,0.f,0.f};
    #pragma unroll
    for (int kb = 0; kb < 4; ++kb) {
        bf16x8 a[4], b[2];
        #pragma unroll
        for (int mb = 0; mb < 4; ++mb)
            a[mb] = *(const bf16x8*)&buf[(mb * 16 + l16) * P2 + kb * 32 + quad * 8];
        #pragma unroll
        for (int nt = 0; nt < 2; ++nt)
            b[nt] = *(const bf16x8*)&PWe2[((kb * 8 + w * 2 + nt) * 64 + lane) * 8];
        #pragma unroll
        for (int mb = 0; mb < 4; ++mb)
            #pragma unroll
            for (int nt = 0; nt < 2; ++nt)
                acc2[mb][nt] = __builtin_amdgcn_mfma_f32_16x16x32_bf16(
                    a[mb], b[nt], acc2[mb][nt], 0, 0, 0);
    }
    __syncthreads();   // all sT reads done -> buf reusable as sM

    {
        const float2 b2 = *(const float2*)&be2[cb];
        #pragma unroll
        for (int mb = 0; mb < 4; ++mb)
            #pragma unroll
            for (int r = 0; r < 4; ++r) {
                const int row = mb * 16 + quad * 4 + r;
                *(unsigned*)&buf[row * P2 + cb] =
                    pack2bf(silu_f(acc2[mb][0][r] + b2.x),
                            silu_f(acc2[mb][1][r] + b2.y));
            }
    }
    __syncthreads();

    // msg: dst-sorted run reduction (reads buf as sM)
    {
        const int cp = t & 63;
        const int r0 = (t >> 6) * 16;
        float a0 = 0.0f, a1 = 0.0f;
        #pragma unroll 4
        for (int r = 0; r < 16; ++r) {
            const int row = r0 + r;
            const int d   = sDst[row];
            const unsigned u = *(const unsigned*)&buf[row * P2 + 2 * cp];
            a0 += bf2f((unsigned short)(u & 0xffff));
            a1 += bf2f((unsigned short)(u >> 16));
            const bool flush = (r == 15) || (sDst[row + 1] != d);
            if (flush) {
                atomicAdd(&msg_agg[(size_t)d * HD + 2 * cp], a0);
                atomicAdd(&msg_agg[(size_t)d * HD + 2 * cp + 1], a1);
                a0 = 0.0f; a1 = 0.0f;
            }
        }
    }

    // GEMM3: m @ Wx1 (reads buf as sM)
    f32x4 acc3[4][2];
    #pragma unroll
    for (int mb = 0; mb < 4; ++mb)
        #pragma unroll
        for (int nt = 0; nt < 2; ++nt) acc3[mb][nt] = (f32x4){0.f,0.f,0.f,0.f};
    #pragma unroll
    for (int kb = 0; kb < 4; ++kb) {
        bf16x8 a[4], b[2];
        #pragma unroll
        for (int mb = 0; mb < 4; ++mb)
            a[mb] = *(const bf16x8*)&buf[(mb * 16 + l16) * P2 + kb * 32 + quad * 8];
        #pragma unroll
        for (int nt = 0; nt < 2; ++nt)
            b[nt] = *(const bf16x8*)&PWx1[((kb * 8 + w * 2 + nt) * 64 + lane) * 8];
        #pragma unroll
        for (int mb = 0; mb < 4; ++mb)
            #pragma unroll
            for (int nt = 0; nt < 2; ++nt)
                acc3[mb][nt] = __builtin_amdgcn_mfma_f32_16x16x32_bf16(
                    a[mb], b[nt], acc3[mb][nt], 0, 0, 0);
    }
    float p[4][4];
    {
        const float2 bx = *(const float2*)&bx1[cb];
        const float2 w2 = *(const float2*)&Wx2[cb];
        #pragma unroll
        for (int mb = 0; mb < 4; ++mb)
            #pragma unroll
            for (int r = 0; r < 4; ++r)
                p[mb][r] = silu_f(acc3[mb][0][r] + bx.x) * w2.x +
                           silu_f(acc3[mb][1][r] + bx.y) * w2.y;
        #pragma unroll
        for (int off = 8; off >= 1; off >>= 1)
            #pragma unroll
            for (int mb = 0; mb < 4; ++mb)
                #pragma unroll
                for (int r = 0; r < 4; ++r)
                    p[mb][r] += __shfl_xor(p[mb][r], off, 64);
    }
    __syncthreads();   // all sM reads (msg + GEMM3) done -> buf reusable as red

    if (l16 == 0) {
        float* red = reinterpret_cast<float*>(buf);
        #pragma unroll
        for (int mb = 0; mb < 4; ++mb)
            #pragma unroll
            for (int r = 0; r < 4; ++r)
                red[w * 64 + mb * 16 + quad * 4 + r] = p[mb][r];
    }
    __syncthreads();
    if (t < 64) {
        const float* red = reinterpret_cast<const float*>(buf);
        sW[t] = tanh_f(red[t] + red[64 + t] + red[128 + t] + red[192 + t] + bx2[0]);
    }
    __syncthreads();

    // coord: per-wave segmented shuffle reduction
    if (w < 3) {
        const int dstv = sDst[lane];
        float v = sDiff[lane][w] * sW[lane];
        #pragma unroll
        for (int off = 1; off <= 32; off <<= 1) {
            const int   dn = __shfl_down(dstv, off, 64);
            const float vn = __shfl_down(v, off, 64);
            if (lane + off < 64 && dn == dstv) v += vn;
        }
        const int up = __shfl_up(dstv, 1, 64);
        if (lane == 0 || up != dstv)
            atomicAdd(&coord_agg[(size_t)dstv * 3 + w], v);
    }
}

// ============ node kernel ============
__global__ __launch_bounds__(256, 4) void egnn_node_kernel(
    const unsigned short* __restrict__ hb, const float* __restrict__ h,
    const float* __restrict__ x, const int* __restrict__ fixed_mask,
    const unsigned short* __restrict__ PWh1, const float* __restrict__ bh1,
    const unsigned short* __restrict__ PWh2, const float* __restrict__ bh2,
    const float* __restrict__ msg_agg, const float* __restrict__ coord_agg,
    float* __restrict__ out_h, float* __restrict__ out_x)
{
    __shared__ __align__(16) unsigned short sTn[64 * P2];
    const int t  = threadIdx.x;
    const int n0 = blockIdx.x * 64;
    const int lane = t & 63, w = t >> 6;
    const int quad = lane >> 4, l16 = lane & 15;

    if (t < 192) {
        const int ln = t / 3, d3 = t - ln * 3;
        const int n  = n0 + ln;
        if (n < NN) {
            const float add = (fixed_mask[n] != 0) ? 0.0f : coord_agg[(size_t)n*3 + d3];
            out_x[(size_t)n*3 + d3] = x[(size_t)n*3 + d3] + add;
        }
    }

    int nrow[4];
    #pragma unroll
    for (int mb = 0; mb < 4; ++mb) nrow[mb] = min(n0 + mb * 16 + l16, NN - 1);

    f32x4 acc[4][2];
    #pragma unroll
    for (int mb = 0; mb < 4; ++mb)
        #pragma unroll
        for (int nt = 0; nt < 2; ++nt) acc[mb][nt] = (f32x4){0.f,0.f,0.f,0.f};

    #pragma unroll
    for (int kb = 0; kb < 8; ++kb) {
        bf16x8 a[4], b[2];
        if (kb < 4) {
            #pragma unroll
            for (int mb = 0; mb < 4; ++mb)
                a[mb] = *(const bf16x8*)&hb[(size_t)nrow[mb] * HD + kb * 32 + quad * 8];
        } else {
            #pragma unroll
            for (int mb = 0; mb < 4; ++mb) {
                const float* mp = msg_agg + (size_t)nrow[mb] * HD + (kb - 4) * 32 + quad * 8;
                const float4 v0 = ((const float4*)mp)[0];
                const float4 v1 = ((const float4*)mp)[1];
                bf16x8 av;
                av[0]=(__bf16)v0.x; av[1]=(__bf16)v0.y; av[2]=(__bf16)v0.z; av[3]=(__bf16)v0.w;
                av[4]=(__bf16)v1.x; av[5]=(__bf16)v1.y; av[6]=(__bf16)v1.z; av[7]=(__bf16)v1.w;
                a[mb] = av;
            }
        }
        #pragma unroll
        for (int nt = 0; nt < 2; ++nt)
            b[nt] = *(const bf16x8*)&PWh1[((kb * 8 + w * 2 + nt) * 64 + lane) * 8];
        #pragma unroll
        for (int mb = 0; mb < 4; ++mb)
            #pragma unroll
            for (int nt = 0; nt < 2; ++nt)
                acc[mb][nt] = __builtin_amdgcn_mfma_f32_16x16x32_bf16(
                    a[mb], b[nt], acc[mb][nt], 0, 0, 0);
    }
    #pragma unroll
    for (int nt = 0; nt < 2; ++nt) {
        const int col = w * 32 + nt * 16 + l16;
        const float bias = bh1[col];
        #pragma unroll
        for (int mb = 0; mb < 4; ++mb)
            #pragma unroll
            for (int r = 0; r < 4; ++r) {
                const int row = mb * 16 + quad * 4 + r;
                sTn[row * P2 + col] = f2bf(silu_f(acc[mb][nt][r] + bias));
            }
    }
    __syncthreads();

    #pragma unroll
    for (int mb = 0; mb < 4; ++mb)
        #pragma unroll
        for (int nt = 0; nt < 2; ++nt) acc[mb][nt] = (f32x4){0.f,0.f,0.f,0.f};
    #pragma unroll
    for (int kb = 0; kb < 4; ++kb) {
        bf16x8 a[4], b[2];
        #pragma unroll
        for (int mb = 0; mb < 4; ++mb)
            a[mb] = *(const bf16x8*)&sTn[(mb * 16 + l16) * P2 + kb * 32 + quad * 8];
        #pragma unroll
        for (int nt = 0; nt < 2; ++nt)
            b[nt] = *(const bf16x8*)&PWh2[((kb * 8 + w * 2 + nt) * 64 + lane) * 8];
        #pragma unroll
        for (int mb = 0; mb < 4; ++mb)
            #pragma unroll
            for (int nt = 0; nt < 2; ++nt)
                acc[mb][nt] = __builtin_amdgcn_mfma_f32_16x16x32_bf16(
                    a[mb], b[nt], acc[mb][nt], 0, 0, 0);
    }
    #pragma unroll
    for (int nt = 0; nt < 2; ++nt) {
        const int col = w * 32 + nt * 16 + l16;
        const float bias = bh2[col];
        #pragma unroll
        for (int mb = 0; mb < 4; ++mb)
            #pragma unroll
            for (int r = 0; r < 4; ++r) {
                const int row = mb * 16 + quad * 4 + r;
                const int n   = n0 + row;
                if (n < NN)
                    out_h[(size_t)n * HD + col] =
                        h[(size_t)n * HD + col] + acc[mb][nt][r] + bias;
            }
    }
}

extern "C" void kernel_launch(void* const* d_in, const int* in_sizes, int n_in,
                              void* d_out, int out_size, void* d_ws, size_t ws_size,
                              hipStream_t stream)
{
    const float* h     = (const float*)d_in[0];
    const float* x     = (const float*)d_in[1];
    const int*   ei    = (const int*)d_in[2];
    const float* eattr = (const float*)d_in[3];
    const int*   fmask = (const int*)d_in[4];
    const float* We1   = (const float*)d_in[5];
    const float* be1   = (const float*)d_in[6];
    const float* We2   = (const float*)d_in[7];
    const float* be2   = (const float*)d_in[8];
    const float* Wx1   = (const float*)d_in[9];
    const float* bx1   = (const float*)d_in[10];
    const float* Wx2   = (const float*)d_in[11];
    const float* bx2   = (const float*)d_in[12];
    const float* Wh1   = (const float*)d_in[13];
    const float* bh1   = (const float*)d_in[14];
    const float* Wh2   = (const float*)d_in[15];
    const float* bh2   = (const float*)d_in[16];

    // ws: [msg | coord] zeroed by prep, [cnt] by tiny memset, then the rest
    float* msg    = (float*)d_ws;                        // NN*HD
    float* coord  = msg + (size_t)NN * HD;               // NN*3
    int*   cnt    = (int*)(coord + (size_t)NN * 3);      // NN
    int*   cursor = cnt + NN;                            // NN
    int*   perm   = cursor + NN;                         // NE
    unsigned short* hb    = (unsigned short*)(perm + NE);
    unsigned short* preS  = hb + (size_t)NN * HD;
    unsigned short* preD  = preS + (size_t)NN * HD;
    unsigned short* PWt   = preD + (size_t)NN * HD;
    unsigned short* PWe1m = PWt + S_PWT;
    unsigned short* PWe2  = PWe1m + S_PWE1M;
    unsigned short* PWx1  = PWe2 + S_PW4;
    unsigned short* PWh1  = PWx1 + S_PW4;
    unsigned short* PWh2  = PWh1 + S_PWH1;

    float* out_h = (float*)d_out;
    float* out_x = out_h + (size_t)NN * HD;

    hipMemsetAsync(cnt, 0, (size_t)NN * sizeof(int), stream);
    egnn_prep_kernel<<<1024, 256, 0, stream>>>(
        h, ei, We1, We2, Wx1, Wh1, Wh2, (int*)d_ws,
        hb, PWt, PWe1m, PWe2, PWx1, PWh1, PWh2, cnt);
    egnn_pre_kernel<<<314, 256, 0, stream>>>(hb, PWe1m, be1, cnt, cursor, preS, preD);
    egnn_perm_kernel<<<NE / 256, 256, 0, stream>>>(ei, cursor, perm);
    egnn_edge_kernel<<<NE / 64, 256, 0, stream>>>(
        preS, preD, x, ei, eattr, perm, PWt, PWe2, be2, PWx1, bx1,
        Wx2, bx2, msg, coord);
    egnn_node_kernel<<<(NN + 63) / 64, 256, 0, stream>>>(
        hb, h, x, fmask, PWh1, bh1, PWh2, bh2, msg, coord, out_h, out_x);
}